// Round 7
// baseline (191.986 us; speedup 1.0000x reference)
//
#include <hip/hip_runtime.h>
#include <cfloat>
#include <climits>

#define BATCH 4
#define KQ    2048
#define NP    4096
#define CIN   64
#define CMID  32
#define NB    16
#define NBINS 4096   // bits >> 19 : 8 exp bits + 4 mantissa bits
#define CANDCAP 256

typedef short   bf16x8  __attribute__((ext_vector_type(8)));
typedef float   floatx4 __attribute__((ext_vector_type(4)));

__device__ __forceinline__ unsigned short f2bf(float f) {
  unsigned u = __float_as_uint(f);
  u = (u + 0x7fffu + ((u >> 16) & 1u)) >> 16;   // RNE, inputs finite
  return (unsigned short)u;
}
__device__ __forceinline__ float bf2f(unsigned short u) {
  return __uint_as_float((unsigned)u << 16);
}

// async global->LDS, 16B per lane; LDS dst = base + lane*16 (wave-uniform base)
__device__ __forceinline__ void load_lds16(const void* g, void* l) {
  __builtin_amdgcn_global_load_lds(
      (const __attribute__((address_space(1))) unsigned int*)g,
      (__attribute__((address_space(3))) unsigned int*)l, 16, 0, 0);
}

// ---------------------------------------------------------------------------
// Kernel 1 (fused): per query (1 block): radix-select top-16 -> edge MLP ->
// e row (bf16). Blocks 0..543 additionally transpose fc0_W/fc1_W to bf16.
// The 16 KB hist region is unioned (transpose scratch / hist / h2+m+f bufs,
// temporally disjoint, barrier-separated).
// ---------------------------------------------------------------------------
__global__ __launch_bounds__(256) void select_edge(
    const float* __restrict__ keys, const float* __restrict__ points,
    const float* __restrict__ feats,
    const float* __restrict__ wc0_W, const float* __restrict__ wc0_b,
    const float* __restrict__ wc1_W, const float* __restrict__ wc1_b,
    const float* __restrict__ wc2_W, const float* __restrict__ wc2_b,
    const float* __restrict__ fc0_W, const float* __restrict__ fc1_W,
    unsigned short* __restrict__ W0T, unsigned short* __restrict__ W1T,
    unsigned short* __restrict__ E) {
  __shared__ __align__(16) char uni[NBINS * 4];        // 16 KB union
  int*   hist = reinterpret_cast<int*>(uni);
  float (*tt)[33] = reinterpret_cast<float(*)[33]>(uni);
  float (*h2_all)[33] = reinterpret_cast<float(*)[33]>(uni);              // 2112 B
  unsigned short (*m_bf)[34] =
      reinterpret_cast<unsigned short(*)[34]>(uni + 2112);                // 1088 B
  unsigned short (*f_bf)[72] =
      reinterpret_cast<unsigned short(*)[72]>(uni + 3200);                // 2304 B

  __shared__ int   psum[256];
  __shared__ float cand_d[CANDCAP];
  __shared__ int   cand_i[CANDCAP];
  __shared__ int   nidx[NB];
  __shared__ int   sel_cnt, cand_cnt, sBin, sCbelow;
  __shared__ float w0[96], b0v[32], w1[1024], b1v[32], w2[1024], b2v[32];

  const int tid = threadIdx.x;
  const int bid = blockIdx.x;
  const int b   = bid >> 11;

  // ---- P0: folded weight transposes (f32 [K][N] -> bf16 [N][K]) ----
  if (bid < 544) {
    const float* W; unsigned short* WT; int K, N, k0, n0;
    if (bid < 512) { W = fc0_W; WT = W0T; K = 2048; N = 256;
                     k0 = (bid >> 3) * 32; n0 = (bid & 7) * 32; }
    else           { W = fc1_W; WT = W1T; K = 256;  N = 128;
                     k0 = ((bid - 512) >> 2) * 32; n0 = ((bid - 512) & 3) * 32; }
    const int tx = tid & 31, ty = tid >> 5;
#pragma unroll
    for (int p = 0; p < 4; ++p)
      tt[ty + p * 8][tx] = W[(size_t)(k0 + ty + p * 8) * N + n0 + tx];
    __syncthreads();
#pragma unroll
    for (int p = 0; p < 4; ++p)
      WT[(size_t)(n0 + ty + p * 8) * K + k0 + tx] = f2bf(tt[tx][ty + p * 8]);
    __syncthreads();   // uni free again
  }

  // ---- P1: stage MLP weights, zero hist, init counters ----
  if (tid < 96) w0[tid] = wc0_W[tid];
  for (int i = tid; i < 1024; i += 256) { w1[i] = wc1_W[i]; w2[i] = wc2_W[i]; }
  if (tid < 32) { b0v[tid] = wc0_b[tid]; b1v[tid] = wc1_b[tid]; b2v[tid] = wc2_b[tid]; }
  for (int i = tid; i < NBINS; i += 256) hist[i] = 0;
  if (tid == 0) { sel_cnt = 0; cand_cnt = 0; }

  const float kx = keys[bid * 3 + 0];
  const float ky = keys[bid * 3 + 1];
  const float kz = keys[bid * 3 + 2];
  __syncthreads();

  // ---- P2: thread owns 16 consecutive points (12 float4 loads) + hist ----
  const float4* pv =
      reinterpret_cast<const float4*>(points + (size_t)b * NP * 3) + (size_t)tid * 12;
  float f[48];
#pragma unroll
  for (int c = 0; c < 12; ++c) {
    const float4 v = pv[c];
    f[c * 4 + 0] = v.x; f[c * 4 + 1] = v.y; f[c * 4 + 2] = v.z; f[c * 4 + 3] = v.w;
  }
  float dreg[16];
#pragma unroll
  for (int j = 0; j < 16; ++j) {
    const float dx = f[j * 3 + 0] - kx;
    const float dy = f[j * 3 + 1] - ky;
    const float dz = f[j * 3 + 2] - kz;
    const float d  = dx * dx + dy * dy + dz * dz;
    dreg[j] = d;
    atomicAdd(&hist[__float_as_uint(d) >> 19], 1);
  }
  __syncthreads();

  // ---- P3: two-level threshold scan ----
  {
    const int base = tid * 16;
    int s = 0;
#pragma unroll
    for (int j = 0; j < 16; ++j) s += hist[base + j];
    psum[tid] = s;
  }
  __syncthreads();

  if (tid < 64) {
    const int q = psum[tid * 4] + psum[tid * 4 + 1] + psum[tid * 4 + 2] + psum[tid * 4 + 3];
    int incl = q;
#pragma unroll
    for (int off = 1; off < 64; off <<= 1) {
      int u = __shfl_up(incl, off);
      if (tid >= off) incl += u;
    }
    unsigned long long bal = __ballot(incl >= NB);
    int firstlane = __ffsll((long long)bal) - 1;
    if (tid == firstlane) {
      int cum = incl - q;
      int bin = -1;
      for (int t = 0; t < 4 && bin < 0; ++t) {
        const int ps = psum[tid * 4 + t];
        if (cum + ps >= NB) {
          const int b0 = (tid * 4 + t) * 16;
          for (int j = 0; j < 16; ++j) {
            const int h = hist[b0 + j];
            if (cum + h >= NB) { bin = b0 + j; break; }
            cum += h;
          }
        } else cum += ps;
      }
      sBin = bin; sCbelow = cum;
    }
  }
  __syncthreads();

  // ---- P4: collect ----
  const unsigned B = (unsigned)sBin;
#pragma unroll
  for (int j = 0; j < 16; ++j) {
    const int i = tid * 16 + j;
    const unsigned bk = __float_as_uint(dreg[j]) >> 19;
    if (bk < B) {
      int pos = atomicAdd(&sel_cnt, 1);
      nidx[pos] = i;
    } else if (bk == B) {
      int pos = atomicAdd(&cand_cnt, 1);
      if (pos < CANDCAP) { cand_d[pos] = dreg[j]; cand_i[pos] = i; }
    }
  }
  __syncthreads();

  // ---- P5: boundary-bin argmin (tie -> lower index) ----
  if (tid < 64) {
    const int rem = NB - sCbelow;
    const int cc  = min(cand_cnt, CANDCAP);
    for (int s = 0; s < rem; ++s) {
      float bd = FLT_MAX; int bi = INT_MAX; int bp = -1;
      for (int j = tid; j < cc; j += 64) {
        float d = cand_d[j]; int ii = cand_i[j];
        if (d < bd || (d == bd && ii < bi)) { bd = d; bi = ii; bp = j; }
      }
#pragma unroll
      for (int off = 32; off > 0; off >>= 1) {
        float od = __shfl_down(bd, off);
        int   oi = __shfl_down(bi, off);
        int   op = __shfl_down(bp, off);
        if (od < bd || (od == bd && oi < bi)) { bd = od; bi = oi; bp = op; }
      }
      if (tid == 0) { nidx[sCbelow + s] = bi; cand_d[bp] = FLT_MAX; }
    }
  }
  __syncthreads();   // hist region dead from here (h2/m/f alias it)

  // ---- P6: edge MLP, stage 1+2. thread = (edge e, output-pair o2) ----
  const int e  = tid & 15;
  const int o2 = tid >> 4;          // 0..15 -> outputs 2*o2, 2*o2+1
  const int idx = nidx[e];
  {
    const float* p = points + ((size_t)b * NP + idx) * 3;
    const float rx = p[0] - kx, ry = p[1] - ky, rz = p[2] - kz;
    float h1[32];
#pragma unroll
    for (int o = 0; o < 32; ++o)
      h1[o] = fmaxf(0.f, rx * w0[o] + ry * w0[32 + o] + rz * w0[64 + o] + b0v[o]);
#pragma unroll
    for (int j = 0; j < 2; ++j) {
      const int o = o2 * 2 + j;
      float a = b1v[o];
#pragma unroll
      for (int i = 0; i < 32; ++i) a += h1[i] * w1[i * 32 + o];
      h2_all[e][o] = fmaxf(a, 0.f);
    }
  }
  __syncthreads();

  // ---- P7: m outputs (reads h2_all, writes m_bf) + f staging ----
  {
    float mo[2];
#pragma unroll
    for (int j = 0; j < 2; ++j) {
      const int o = o2 * 2 + j;
      float a = b2v[o];
#pragma unroll
      for (int i = 0; i < 32; ++i) a += h2_all[e][i] * w2[i * 32 + o];
      mo[j] = a;
    }
    const unsigned lo = f2bf(mo[0]), hi = f2bf(mo[1]);
    *reinterpret_cast<unsigned*>(&m_bf[e][o2 * 2]) = lo | (hi << 16);

    // f staging: row = tid>>4, ch = tid&15 (256 tasks, 1/thread)
    const int row = tid >> 4, ch = tid & 15;
    const float4 v = *reinterpret_cast<const float4*>(
        feats + ((size_t)b * NP + nidx[row]) * CIN + ch * 4);
    ushort4 o4;
    o4.x = f2bf(v.x); o4.y = f2bf(v.y); o4.z = f2bf(v.z); o4.w = f2bf(v.w);
    *reinterpret_cast<ushort4*>(&f_bf[row][ch * 4]) = o4;
  }
  __syncthreads();

  // ---- P8: e-comp. thread = (mid = tid>>3, c-octet = tid&7) ----
  {
    const int mid = tid >> 3;
    const int c0  = (tid & 7) * 8;
    float acc[8] = {};
#pragma unroll
    for (int n = 0; n < 16; ++n) {
      const float mv = bf2f(m_bf[n][mid]);
      const uint4 fv = *reinterpret_cast<const uint4*>(&f_bf[n][c0]);
      float fc[8];
      fc[0] = __uint_as_float(fv.x << 16); fc[1] = __uint_as_float(fv.x & 0xffff0000u);
      fc[2] = __uint_as_float(fv.y << 16); fc[3] = __uint_as_float(fv.y & 0xffff0000u);
      fc[4] = __uint_as_float(fv.z << 16); fc[5] = __uint_as_float(fv.z & 0xffff0000u);
      fc[6] = __uint_as_float(fv.w << 16); fc[7] = __uint_as_float(fv.w & 0xffff0000u);
#pragma unroll
      for (int j = 0; j < 8; ++j) acc[j] += mv * fc[j];
    }
    uint4 o;
    o.x = (unsigned)f2bf(acc[0]) | ((unsigned)f2bf(acc[1]) << 16);
    o.y = (unsigned)f2bf(acc[2]) | ((unsigned)f2bf(acc[3]) << 16);
    o.z = (unsigned)f2bf(acc[4]) | ((unsigned)f2bf(acc[5]) << 16);
    o.w = (unsigned)f2bf(acc[6]) | ((unsigned)f2bf(acc[7]) << 16);
    *reinterpret_cast<uint4*>(&E[(size_t)bid * 2048 + mid * 64 + c0]) = o;
  }
}

// ---------------------------------------------------------------------------
// Kernel 2/3: MFMA GEMM  C = act(A[M,KDIM]bf16 @ Bt[N,KDIM]^T + bias)
// 64x64 tile (4 waves x 32x32), BK=128, global_load_lds width-16 staging,
// XOR chunk swizzle for conflict-free ds_read_b128.
// ---------------------------------------------------------------------------
template <int KDIM, bool RELU, bool OUTBF16>
__global__ __launch_bounds__(256) void gemm_mfma(
    const unsigned short* __restrict__ A,   // [M][KDIM] bf16
    const unsigned short* __restrict__ Bt,  // [N][KDIM] bf16
    const float* __restrict__ bias,
    void* __restrict__ Cout, int ldc) {
  __shared__ __align__(16) unsigned short Al[64 * 128];  // 16 KB
  __shared__ __align__(16) unsigned short Bl[64 * 128];  // 16 KB
  const int tid  = threadIdx.x;
  const int m0   = blockIdx.x * 64, n0 = blockIdx.y * 64;
  const int wv   = tid >> 6, lane = tid & 63;
  const int quad = lane >> 4, s = lane & 15;
  const int moff = (wv & 1) * 32, noff = (wv >> 1) * 32;
  const int lr   = lane >> 4;     // staging: row within 4-row group
  const int lc   = lane & 15;     // staging: 16B chunk within row

  floatx4 acc[2][2] = {{{0.f,0.f,0.f,0.f},{0.f,0.f,0.f,0.f}},
                       {{0.f,0.f,0.f,0.f},{0.f,0.f,0.f,0.f}}};

  for (int k0 = 0; k0 < KDIM; k0 += 128) {
#pragma unroll
    for (int t = 0; t < 4; ++t) {
      const int R0 = wv * 16 + t * 4;          // wave-uniform base row
      const int r  = R0 + lr;
      const int gc = lc ^ (r & 7);
      load_lds16(A  + (size_t)(m0 + r) * KDIM + k0 + gc * 8, &Al[R0 * 128]);
      load_lds16(Bt + (size_t)(n0 + r) * KDIM + k0 + gc * 8, &Bl[R0 * 128]);
    }
    __syncthreads();
#pragma unroll
    for (int h = 0; h < 4; ++h) {
      bf16x8 af[2], bfr[2];
#pragma unroll
      for (int i = 0; i < 2; ++i) {
        const int r = moff + i * 16 + s;
        af[i] = *reinterpret_cast<const bf16x8*>(
            &Al[(size_t)r * 128 + ((((h << 2) | quad) ^ (r & 7)) << 3)]);
      }
#pragma unroll
      for (int j = 0; j < 2; ++j) {
        const int r = noff + j * 16 + s;
        bfr[j] = *reinterpret_cast<const bf16x8*>(
            &Bl[(size_t)r * 128 + ((((h << 2) | quad) ^ (r & 7)) << 3)]);
      }
#pragma unroll
      for (int i = 0; i < 2; ++i)
#pragma unroll
        for (int j = 0; j < 2; ++j)
          acc[i][j] = __builtin_amdgcn_mfma_f32_16x16x32_bf16(af[i], bfr[j], acc[i][j], 0, 0, 0);
    }
    __syncthreads();
  }

#pragma unroll
  for (int i = 0; i < 2; ++i)
#pragma unroll
    for (int j = 0; j < 2; ++j) {
      const int col = n0 + noff + j * 16 + s;
      const float bv = bias[col];
#pragma unroll
      for (int r = 0; r < 4; ++r) {
        const int row = m0 + moff + i * 16 + quad * 4 + r;
        float v = acc[i][j][r] + bv;
        if (RELU) v = fmaxf(v, 0.f);
        if (OUTBF16)
          ((unsigned short*)Cout)[(size_t)row * ldc + col] = f2bf(v);
        else
          ((float*)Cout)[(size_t)row * ldc + col] = v;
      }
    }
}

// ---------------------------------------------------------------------------
extern "C" void kernel_launch(void* const* d_in, const int* in_sizes, int n_in,
                              void* d_out, int out_size, void* d_ws, size_t ws_size,
                              hipStream_t stream) {
  const float* keys   = (const float*)d_in[0];
  const float* points = (const float*)d_in[1];
  const float* feats  = (const float*)d_in[2];
  const float* wc0_W  = (const float*)d_in[3];
  const float* wc0_b  = (const float*)d_in[4];
  const float* wc1_W  = (const float*)d_in[5];
  const float* wc1_b  = (const float*)d_in[6];
  const float* wc2_W  = (const float*)d_in[7];
  const float* wc2_b  = (const float*)d_in[8];
  const float* fc0_W  = (const float*)d_in[9];
  const float* fc0_b  = (const float*)d_in[10];
  const float* fc1_W  = (const float*)d_in[11];
  const float* fc1_b  = (const float*)d_in[12];
  float* out = (float*)d_out;

  const int M = BATCH * KQ;   // 8192
  char* ws = (char*)d_ws;
  unsigned short* E    = (unsigned short*)(ws);                    // 32 MB
  unsigned short* H16  = (unsigned short*)(ws + (size_t)33554432); //  4 MB
  unsigned short* W0T  = (unsigned short*)(ws + (size_t)37748736); //  1 MB
  unsigned short* W1T  = (unsigned short*)(ws + (size_t)38797312); // 64 KB

  select_edge<<<M, 256, 0, stream>>>(keys, points, feats,
                                     wc0_W, wc0_b, wc1_W, wc1_b, wc2_W, wc2_b,
                                     fc0_W, fc1_W, W0T, W1T, E);
  gemm_mfma<2048, true,  true ><<<dim3(M / 64, 4), 256, 0, stream>>>(E, W0T, fc0_b, H16, 256);
  gemm_mfma<256,  false, false><<<dim3(M / 64, 2), 256, 0, stream>>>(H16, W1T, fc1_b, out, 128);
}